// Round 1
// baseline (16417.268 us; speedup 1.0000x reference)
//
#include <hip/hip_runtime.h>
#include <stdint.h>

#define BB 384
#define LSEQ 64
#define HH 300
#define TD 64
#define TT 126
#define SS 65           // L+1
#define G4 256          // 4*TD
#define G5 1500         // 5*H
#define KG 964          // 900 + 64
#define KP 900
#define SEQB 38400      // LSEQ*2*H

typedef unsigned int u32;

__device__ __forceinline__ float sigm(float x){ return 1.0f/(1.0f + __expf(-x)); }

// ---------- prep: per-row transition walk (control flow is data-independent) ----------
__global__ void k_prep(const int* __restrict__ trans, u32* __restrict__ idxarr, int* __restrict__ spf)
{
    int b = threadIdx.x;
    if (b >= BB) return;
    int sp = 2, bp = 0;
    for (int t = 0; t < TT; ++t) {
        int tr = trans[b*TT + t];
        int red  = (tr==2 || tr==3) ? 1 : 0;
        int left = (tr==2) ? 1 : 0;
        int s1 = sp-1; s1 = s1 < 0 ? 0 : (s1 > SS-1 ? SS-1 : s1);
        int s2 = sp-2; s2 = s2 < 0 ? 0 : (s2 > SS-1 ? SS-1 : s2);
        int wp = red ? sp-2 : sp; wp = wp < 0 ? 0 : (wp > SS-1 ? SS-1 : wp);
        int bf = bp; bf = bf > LSEQ-1 ? LSEQ-1 : bf;
        idxarr[t*BB + b] = (u32)s1 | ((u32)s2<<7) | ((u32)bf<<14) | ((u32)wp<<21)
                         | ((u32)red<<28) | ((u32)left<<29);
        sp += red ? -1 : 1;
        if (sp < 1) sp = 1;
        bp += (tr==1) ? 1 : 0;
    }
    int o = sp-1; o = o < 0 ? 0 : (o > SS-1 ? SS-1 : o);
    spf[b] = o;
}

// ---------- init: stack (pos 0,1 = token0, rest 0), th/tc state ----------
__global__ void k_init(const float* __restrict__ seq, const float* __restrict__ th0,
                       const float* __restrict__ tc0,
                       float* __restrict__ stack_h, float* __restrict__ stack_c,
                       float* __restrict__ th_buf, float* __restrict__ tc_a)
{
    int i = blockIdx.x*blockDim.x + threadIdx.x;
    int stride = gridDim.x*blockDim.x;
    int n = BB*SS*HH;
    for (int idx = i; idx < n; idx += stride) {
        int b = idx / (SS*HH);
        int r = idx - b*(SS*HH);
        int s = r / HH;
        int c = r - s*HH;
        float vh = 0.f, vc = 0.f;
        if (s < 2) { vh = seq[b*SEQB + c]; vc = seq[b*SEQB + HH + c]; }
        stack_h[idx] = vh; stack_c[idx] = vc;
    }
    for (int idx = i; idx < BB*TD; idx += stride) {
        th_buf[idx] = th0[idx]; tc_a[idx] = tc0[idx];
    }
}

// ---------- P1: g = [buf,s1,s2,th]@[Wih;Whh]^T + b  and  P = [h,hL,hR]@[Uh;Ul;Ur]^T + Uhb ----------
// blocks 0..95   : g tiles 32x32  (12 rb x 8 cb)
// blocks 96..383 : P tiles 32x64  (12 rb x 24 cb), early-exit if no reduce row in tile
__global__ __launch_bounds__(256) void k_p1(int t,
    const float* __restrict__ seq, const u32* __restrict__ idxarr,
    const float* __restrict__ th_buf,
    const float* __restrict__ Wih, const float* __restrict__ Whh,
    const float* __restrict__ bih, const float* __restrict__ bhh,
    const float* __restrict__ Uh, const float* __restrict__ Ul, const float* __restrict__ Ur,
    const float* __restrict__ Uhb,
    const float* __restrict__ stack_h,
    float* __restrict__ gbuf, float* __restrict__ Pbuf)
{
    __shared__ float smem[16*36 + 16*68];
    __shared__ u32 rowmeta[32];
    __shared__ int anyred;
    const int tid = threadIdx.x;
    float* As = smem;            // [16][36] k-major, rows of A tile
    float* Bs = smem + 16*36;    // stride 36 (g) or 68 (P)

    if (blockIdx.x < 96) {
        int rb = blockIdx.x >> 3, cb = blockIdx.x & 7;
        int r0 = rb*32, c0 = cb*32;
        if (tid < 32) rowmeta[tid] = idxarr[t*BB + r0 + tid];
        __syncthreads();
        float acc[2][2] = {};
        const int BSTR = 36;
        for (int kc = 0; kc < KG; kc += 16) {
            int kk = tid & 15;
            int m  = tid >> 4;
            int k = kc + kk;
            #pragma unroll
            for (int p = 0; p < 2; ++p) {
                int mm = m + p*16;
                u32 meta = rowmeta[mm];
                int bb = r0 + mm;
                float v = 0.f;
                if (k < 300) {
                    int bf = (meta >> 14) & 127;
                    v = seq[bb*SEQB + bf*600 + k];
                } else if (k < 600) {
                    int s1 = meta & 127;
                    v = stack_h[(bb*SS + s1)*HH + (k-300)];
                } else if (k < 900) {
                    int s2 = (meta >> 7) & 127;
                    v = stack_h[(bb*SS + s2)*HH + (k-600)];
                } else if (k < KG) {
                    v = th_buf[bb*TD + (k-900)];
                }
                As[kk*36 + mm] = v;
            }
            #pragma unroll
            for (int p = 0; p < 2; ++p) {
                int nn = m + p*16;
                int j = c0 + nn;
                float v = 0.f;
                if (k < 900) v = Wih[j*900 + k];
                else if (k < KG) v = Whh[j*64 + (k-900)];
                Bs[kk*BSTR + nn] = v;
            }
            __syncthreads();
            #pragma unroll
            for (int k2 = 0; k2 < 16; ++k2) {
                float a0 = As[k2*36 + (tid>>4)*2 + 0];
                float a1 = As[k2*36 + (tid>>4)*2 + 1];
                float b0 = Bs[k2*BSTR + (tid&15)*2 + 0];
                float b1 = Bs[k2*BSTR + (tid&15)*2 + 1];
                acc[0][0] += a0*b0; acc[0][1] += a0*b1;
                acc[1][0] += a1*b0; acc[1][1] += a1*b1;
            }
            __syncthreads();
        }
        int row0 = r0 + (tid>>4)*2;
        int col0 = c0 + (tid&15)*2;
        #pragma unroll
        for (int i2 = 0; i2 < 2; ++i2)
        #pragma unroll
        for (int j2 = 0; j2 < 2; ++j2) {
            int j = col0 + j2;
            gbuf[(row0+i2)*G4 + j] = acc[i2][j2] + bih[j] + bhh[j];
        }
    } else {
        int pid = blockIdx.x - 96;
        int rb = pid / 24, cb = pid % 24;
        int r0 = rb*32, c0 = cb*64;
        if (tid < 32) rowmeta[tid] = idxarr[t*BB + r0 + tid];
        if (tid == 0) anyred = 0;
        __syncthreads();
        if (tid < 32 && ((rowmeta[tid] >> 28) & 1)) anyred = 1;
        __syncthreads();
        if (!anyred) return;   // whole tile is shift rows: gates never read
        float acc[2][4] = {};
        const int BSTR = 68;
        for (int kc = 0; kc < KP; kc += 16) {
            int kk = tid & 15;
            int m  = tid >> 4;
            int k = kc + kk;
            #pragma unroll
            for (int p = 0; p < 2; ++p) {
                int mm = m + p*16;
                u32 meta = rowmeta[mm];
                int bb = r0 + mm;
                int left = (meta >> 29) & 1;
                int s1 = meta & 127, s2 = (meta>>7)&127;
                float v = 0.f;
                if (k < 300) {
                    int hs = left ? s1 : s2;
                    v = stack_h[(bb*SS + hs)*HH + k];
                } else if (k < 600) {
                    v = left ? stack_h[(bb*SS + s1)*HH + (k-300)] : 0.f;
                } else if (k < KP) {
                    v = left ? 0.f : stack_h[(bb*SS + s2)*HH + (k-600)];
                }
                As[kk*36 + mm] = v;
            }
            #pragma unroll
            for (int p = 0; p < 4; ++p) {
                int nn = m + p*16;
                int j = c0 + nn;
                float v = 0.f;
                if (j < G5) {
                    if (k < 300) v = Uh[j*300 + k];
                    else if (k < 600) v = Ul[j*300 + (k-300)];
                    else if (k < KP) v = Ur[j*300 + (k-600)];
                }
                Bs[kk*BSTR + nn] = v;
            }
            __syncthreads();
            #pragma unroll
            for (int k2 = 0; k2 < 16; ++k2) {
                float a0 = As[k2*36 + (tid>>4)*2 + 0];
                float a1 = As[k2*36 + (tid>>4)*2 + 1];
                const float* bp_ = &Bs[k2*BSTR + (tid&15)*4];
                float b0=bp_[0], b1=bp_[1], b2=bp_[2], b3=bp_[3];
                acc[0][0]+=a0*b0; acc[0][1]+=a0*b1; acc[0][2]+=a0*b2; acc[0][3]+=a0*b3;
                acc[1][0]+=a1*b0; acc[1][1]+=a1*b1; acc[1][2]+=a1*b2; acc[1][3]+=a1*b3;
            }
            __syncthreads();
        }
        int row0 = r0 + (tid>>4)*2;
        int col0 = c0 + (tid&15)*4;
        #pragma unroll
        for (int i2 = 0; i2 < 2; ++i2)
        #pragma unroll
        for (int j2 = 0; j2 < 4; ++j2) {
            int j = col0 + j2;
            if (j < G5) Pbuf[(row0+i2)*G5 + j] = acc[i2][j2] + Uhb[j];
        }
    }
}

// ---------- P2: tracking LSTM, Q = th@Wc^T, tree-LSTM elementwise, stack write ----------
// 120 blocks: 24 rb (16 rows) x 5 hb (60 cols of H)
__global__ __launch_bounds__(256) void k_p2(int t,
    const float* __restrict__ seq, const u32* __restrict__ idxarr,
    const float* __restrict__ gbuf, const float* __restrict__ Pbuf,
    const float* __restrict__ Wc,
    float* __restrict__ stack_h, float* __restrict__ stack_c,
    float* __restrict__ th_buf, const float* __restrict__ tc_in, float* __restrict__ tc_out)
{
    __shared__ float th_s[16*68];
    __shared__ float Ws[60*68];
    __shared__ u32 rowmeta[16];
    __shared__ int anyred;
    const int tid = threadIdx.x;
    int rb = blockIdx.x / 5, hb = blockIdx.x % 5;
    int r0 = rb*16, c0 = hb*60;

    if (tid < 16) rowmeta[tid] = idxarr[t*BB + r0 + tid];
    if (tid == 0) anyred = 0;
    __syncthreads();
    if (tid < 16 && ((rowmeta[tid] >> 28) & 1)) anyred = 1;

    // tracking LSTM (redundant per hb; hb==0 publishes)
    {
        int row = tid >> 4;
        int d0 = (tid & 15) * 4;
        int b = r0 + row;
        const float* gr = &gbuf[b*G4];
        float4 iv = *(const float4*)&gr[d0];
        float4 fv = *(const float4*)&gr[64 + d0];
        float4 gv = *(const float4*)&gr[128 + d0];
        float4 ov = *(const float4*)&gr[192 + d0];
        float4 tcp = *(const float4*)&tc_in[b*TD + d0];
        float ia[4] = {iv.x,iv.y,iv.z,iv.w};
        float fa[4] = {fv.x,fv.y,fv.z,fv.w};
        float ga[4] = {gv.x,gv.y,gv.z,gv.w};
        float oa[4] = {ov.x,ov.y,ov.z,ov.w};
        float ta[4] = {tcp.x,tcp.y,tcp.z,tcp.w};
        float tcn[4], thn[4];
        #pragma unroll
        for (int u = 0; u < 4; ++u) {
            tcn[u] = sigm(fa[u])*ta[u] + sigm(ia[u])*tanhf(ga[u]);
            thn[u] = sigm(oa[u])*tanhf(tcn[u]);
            th_s[row*68 + d0 + u] = thn[u];
        }
        if (hb == 0) {
            *(float4*)&th_buf[b*TD + d0] = make_float4(thn[0],thn[1],thn[2],thn[3]);
            *(float4*)&tc_out[b*TD + d0] = make_float4(tcn[0],tcn[1],tcn[2],tcn[3]);
        }
    }
    __syncthreads();

    int rowp = tid & 15;
    int cg = tid >> 4;
    int b = r0 + rowp;
    u32 meta = rowmeta[rowp];
    int red = (meta>>28)&1, left = (meta>>29)&1;
    int s1 = meta&127, s2=(meta>>7)&127, bf=(meta>>14)&127, wp=(meta>>21)&127;

    float acc[4][5];
    int nc[4];
    #pragma unroll
    for (int q=0;q<4;++q) nc[q] = cg + 16*q;

    if (anyred) {
        #pragma unroll
        for (int q=0;q<4;++q) if (nc[q] < 60) {
            #pragma unroll
            for (int g5=0; g5<5; ++g5)
                acc[q][g5] = Pbuf[b*G5 + g5*300 + c0 + nc[q]];
        }
        for (int g5=0; g5<5; ++g5) {
            for (int i = tid; i < 60*64; i += 256) {
                int cc = i >> 6, k = i & 63;
                Ws[cc*68 + k] = Wc[(g5*300 + c0 + cc)*TD + k];
            }
            __syncthreads();
            #pragma unroll
            for (int k4 = 0; k4 < 16; ++k4) {
                float4 t4 = *(const float4*)&th_s[rowp*68 + k4*4];
                #pragma unroll
                for (int q=0;q<4;++q) if (nc[q] < 60) {
                    float4 w4 = *(const float4*)&Ws[nc[q]*68 + k4*4];
                    acc[q][g5] += t4.x*w4.x + t4.y*w4.y + t4.z*w4.z + t4.w*w4.w;
                }
            }
            __syncthreads();
        }
    }

    #pragma unroll
    for (int q=0;q<4;++q) {
        if (nc[q] >= 60) continue;
        int c = c0 + nc[q];
        float hv, cv;
        if (red) {
            int chs = left ? s1 : s2;
            float chead = stack_c[(b*SS + chs)*HH + c];
            float cj = sigm(acc[q][0])*tanhf(acc[q][4]) + (sigm(acc[q][2]) + sigm(acc[q][3]))*chead;
            float hj = sigm(acc[q][1])*tanhf(cj);
            hv = hj; cv = cj;
        } else {
            hv = seq[b*SEQB + bf*600 + c];
            cv = seq[b*SEQB + bf*600 + HH + c];
        }
        stack_h[(b*SS + wp)*HH + c] = hv;
        stack_c[(b*SS + wp)*HH + c] = cv;
    }
}

// ---------- output gather ----------
__global__ void k_out(const float* __restrict__ stack_h, const int* __restrict__ spf,
                      float* __restrict__ out)
{
    int i = blockIdx.x*blockDim.x + threadIdx.x;
    if (i >= BB*HH) return;
    int b = i / HH, c = i - b*HH;
    out[i] = stack_h[(b*SS + spf[b])*HH + c];
}

extern "C" void kernel_launch(void* const* d_in, const int* in_sizes, int n_in,
                              void* d_out, int out_size, void* d_ws, size_t ws_size,
                              hipStream_t stream)
{
    const float* seq = (const float*)d_in[0];
    const int*   trans = (const int*)d_in[1];
    const float* Wc  = (const float*)d_in[2];
    const float* Uhw = (const float*)d_in[3];
    const float* Uhb = (const float*)d_in[4];
    const float* Ulw = (const float*)d_in[5];
    const float* Urw = (const float*)d_in[6];
    const float* Wih = (const float*)d_in[7];
    const float* Whh = (const float*)d_in[8];
    const float* bih = (const float*)d_in[9];
    const float* bhh = (const float*)d_in[10];
    const float* th0 = (const float*)d_in[11];
    const float* tc0 = (const float*)d_in[12];
    float* out = (float*)d_out;

    char* w = (char*)d_ws;
    size_t off = 0;
    auto alloc = [&](size_t nbytes) {
        void* p = w + off;
        off = (off + nbytes + 255) & ~(size_t)255;
        return p;
    };
    float* stack_h = (float*)alloc((size_t)BB*SS*HH*4);
    float* stack_c = (float*)alloc((size_t)BB*SS*HH*4);
    float* gbuf    = (float*)alloc((size_t)BB*G4*4);
    float* Pbuf    = (float*)alloc((size_t)BB*G5*4);
    float* th_buf  = (float*)alloc((size_t)BB*TD*4);
    float* tc_a    = (float*)alloc((size_t)BB*TD*4);
    float* tc_b    = (float*)alloc((size_t)BB*TD*4);
    u32*   idxarr  = (u32*)alloc((size_t)TT*BB*4);
    int*   spf     = (int*)alloc((size_t)BB*4);

    k_prep<<<1, 384, 0, stream>>>(trans, idxarr, spf);
    k_init<<<2048, 256, 0, stream>>>(seq, th0, tc0, stack_h, stack_c, th_buf, tc_a);
    for (int t = 0; t < TT; ++t) {
        float* tci = (t & 1) ? tc_b : tc_a;
        float* tco = (t & 1) ? tc_a : tc_b;
        k_p1<<<384, 256, 0, stream>>>(t, seq, idxarr, th_buf, Wih, Whh, bih, bhh,
                                      Uhw, Ulw, Urw, Uhb, stack_h, gbuf, Pbuf);
        k_p2<<<120, 256, 0, stream>>>(t, seq, idxarr, gbuf, Pbuf, Wc,
                                      stack_h, stack_c, th_buf, tci, tco);
    }
    k_out<<<(BB*HH + 255)/256, 256, 0, stream>>>(stack_h, spf, out);
}

// Round 4
// 4255.226 us; speedup vs baseline: 3.8581x; 3.8581x over previous
//
#include <hip/hip_runtime.h>
#include <stdint.h>

#define BB 384
#define LSEQ 64
#define HH 300
#define TDIM 64
#define TT 126
#define NP 63          // pairs
#define KP 320         // padded K per 300-part
#define G4 256
#define G5 1500
#define SEQB 38400     // LSEQ*2*HH

typedef unsigned int u32;
typedef unsigned short ush;
typedef float f32x4 __attribute__((ext_vector_type(4)));
typedef short bf16x8 __attribute__((ext_vector_type(8)));

__device__ __forceinline__ float sigm(float x){ return 1.0f/(1.0f + expf(-x)); }
__device__ __forceinline__ ush f2bf(float x){ u32 u = __float_as_uint(x); u32 r = u + 0x7fff + ((u>>16)&1); return (ush)(r>>16); }
__device__ __forceinline__ float bf2f(ush h){ return __uint_as_float(((u32)h)<<16); }
__device__ __forceinline__ bf16x8 ld16(const ush* p){ return *reinterpret_cast<const bf16x8*>(p); }
__device__ __forceinline__ void mfma16(f32x4& d, bf16x8 a, bf16x8 b){
    d = __builtin_amdgcn_mfma_f32_16x16x32_bf16(a, b, d, 0, 0, 0);
}

// ---------------- weight prep: bf16 hi/lo planes, K padded 300->320 ----------------
__global__ void k_wprep(const float* __restrict__ Uh, const float* __restrict__ Ul,
                        const float* __restrict__ Ur, const float* __restrict__ Wih,
                        const float* __restrict__ Whh,
                        const float* __restrict__ bih, const float* __restrict__ bhh,
                        ush* ULh, ush* ULl, ush* URh, ush* URl,
                        ush* WihH, ush* WihL, ush* WhhH, ush* WhhL, float* bsum)
{
    int i0 = blockIdx.x*blockDim.x + threadIdx.x;
    int stride = gridDim.x*blockDim.x;
    for (int i = i0; i < G5*KP; i += stride) {
        int j = i / KP, k = i - j*KP;
        float vl = 0.f, vr = 0.f;
        if (k < HH) { float u = Uh[j*HH+k]; vl = u + Ul[j*HH+k]; vr = u + Ur[j*HH+k]; }
        ush h;
        h = f2bf(vl); ULh[i] = h; ULl[i] = f2bf(vl - bf2f(h));
        h = f2bf(vr); URh[i] = h; URl[i] = f2bf(vr - bf2f(h));
    }
    for (int i = i0; i < G4*3*KP; i += stride) {
        int j = i / (3*KP), kk = i - j*(3*KP);
        int part = kk / KP, k = kk - part*KP;
        float v = (k < HH) ? Wih[j*900 + part*HH + k] : 0.f;
        ush h = f2bf(v); WihH[i] = h; WihL[i] = f2bf(v - bf2f(h));
    }
    for (int i = i0; i < G4*TDIM; i += stride) {
        float v = Whh[i]; ush h = f2bf(v); WhhH[i] = h; WhhL[i] = f2bf(v - bf2f(h));
    }
    for (int i = i0; i < G4; i += stride) bsum[i] = bih[i] + bhh[i];
}

// ---------------- token h-part -> bf16 hi/lo, [b*64+t][320] ----------------
__global__ void k_cvt(const float* __restrict__ seq, ush* tokH, ush* tokL)
{
    int i0 = blockIdx.x*blockDim.x + threadIdx.x;
    int stride = gridDim.x*blockDim.x;
    for (int i = i0; i < BB*LSEQ*KP; i += stride) {
        int bt = i / KP, k = i - bt*KP;
        int b = bt >> 6, t = bt & 63;
        float v = (k < HH) ? seq[b*SEQB + t*600 + k] : 0.f;
        ush h = f2bf(v); tokH[i] = h; tokL[i] = f2bf(v - bf2f(h));
    }
}

// ---------------- init state ----------------
__global__ void k_init(const float* __restrict__ seq, const float* __restrict__ th0,
                       const float* __restrict__ tc0, const ush* __restrict__ tokH,
                       const ush* __restrict__ tokL,
                       ush* accH, ush* accL, float* acc_c, float* acc_h,
                       ush* thH, ush* thL, float* tc_buf)
{
    int i0 = blockIdx.x*blockDim.x + threadIdx.x;
    int stride = gridDim.x*blockDim.x;
    for (int i = i0; i < BB*KP; i += stride) {          // acc = token0
        int b = i / KP, k = i - b*KP;
        accH[i] = tokH[b*LSEQ*KP + k]; accL[i] = tokL[b*LSEQ*KP + k];
    }
    for (int i = i0; i < BB*HH; i += stride) {
        int b = i / HH, c = i - b*HH;
        acc_c[i] = seq[b*SEQB + HH + c];
        acc_h[i] = seq[b*SEQB + c];
    }
    for (int i = i0; i < BB*TDIM; i += stride) {
        float v = th0[i]; ush h = f2bf(v);
        thH[i] = h; thL[i] = f2bf(v - bf2f(h));
        tc_buf[i] = tc0[i];
    }
}

// ---------------- per-pair left/right permutation ----------------
__global__ __launch_bounds__(448) void k_prep2(const int* __restrict__ trans, int* perm, int* rbarr)
{
    int p = blockIdx.x, t = threadIdx.x;
    __shared__ int cl, cr, rb;
    if (t == 0) { cl = 0; cr = 0; }
    __syncthreads();
    int isleft = 0;
    if (t < BB) {
        isleft = (trans[t*TT + 2*p + 1] == 2);
        if (isleft) atomicAdd(&cl, 1); else atomicAdd(&cr, 1);
    }
    __syncthreads();
    if (t == 0) { rb = ((cl + 63) >> 6) << 6; rbarr[p] = rb; cl = 0; cr = 0; }
    __syncthreads();
    perm[p*448 + t] = -1;
    __syncthreads();
    if (t < BB) {
        int slot = isleft ? atomicAdd(&cl, 1) : rb + atomicAdd(&cr, 1);
        perm[p*448 + slot] = t;
    }
}

// ---------------- kernel A: MFMA GEMMs (GA_even, GA_odd, P) ----------------
// blocks 0..23: GA_even (rows 384, cols 256; A parts {tok_p, acc, tok0} K=320 each + th_prev K=64)
// blocks 24..47: GA_odd  (A parts {tok_{p+1}, tok_p, acc})
// blocks 48..215: P (7 row-tiles x 24 col-tiles of 64x64; left rows vs UL', right vs UR')
__global__ __launch_bounds__(256) void k_pairA(int p,
    const ush* __restrict__ tokH, const ush* __restrict__ tokL,
    const ush* __restrict__ accHp, const ush* __restrict__ accLp,
    const ush* __restrict__ thHp, const ush* __restrict__ thLp,
    const ush* __restrict__ ULh, const ush* __restrict__ ULl,
    const ush* __restrict__ URh, const ush* __restrict__ URl,
    const ush* __restrict__ WihH, const ush* __restrict__ WihL,
    const ush* __restrict__ WhhH, const ush* __restrict__ WhhL,
    const int* __restrict__ perm, const int* __restrict__ rbarr,
    float* __restrict__ gbufE, float* __restrict__ gbufO, float* __restrict__ Pbuf)
{
    const int bid = blockIdx.x, tid = threadIdx.x;
    const int w = tid >> 6, lane = tid & 63;
    const int l15 = lane & 15, kg = lane >> 4;
    f32x4 acc[4];
    #pragma unroll
    for (int cf = 0; cf < 4; ++cf) acc[cf] = (f32x4){0.f,0.f,0.f,0.f};

    if (bid < 48) {
        const int seg = (bid >= 24);
        const int q = bid - seg*24;
        const int rt = q >> 2, ct = q & 3;
        const int r0 = rt*64, c0 = ct*64;
        const int b = r0 + w*16 + l15;
        const ush* aH[3]; const ush* aL[3];
        if (!seg) {
            aH[0] = tokH + (b*64 + p)*KP;   aL[0] = tokL + (b*64 + p)*KP;
            aH[1] = accHp + b*KP;           aL[1] = accLp + b*KP;
            aH[2] = tokH + (b*64)*KP;       aL[2] = tokL + (b*64)*KP;
        } else {
            aH[0] = tokH + (b*64 + p+1)*KP; aL[0] = tokL + (b*64 + p+1)*KP;
            aH[1] = tokH + (b*64 + p)*KP;   aL[1] = tokL + (b*64 + p)*KP;
            aH[2] = accHp + b*KP;           aL[2] = accLp + b*KP;
        }
        const ush* bH[4]; const ush* bL[4];
        #pragma unroll
        for (int cf = 0; cf < 4; ++cf) {
            int j = c0 + cf*16 + l15;
            bH[cf] = WihH + j*(3*KP) + kg*8;
            bL[cf] = WihL + j*(3*KP) + kg*8;
        }
        #pragma unroll
        for (int part = 0; part < 3; ++part) {
            const ush* pah = aH[part] + kg*8;
            const ush* pal = aL[part] + kg*8;
            const int ko = part*KP;
            #pragma unroll
            for (int kc = 0; kc < KP; kc += 32) {
                bf16x8 ah = ld16(pah + kc);
                bf16x8 al = ld16(pal + kc);
                bf16x8 b0 = ld16(bH[0]+ko+kc), b1 = ld16(bH[1]+ko+kc), b2 = ld16(bH[2]+ko+kc), b3 = ld16(bH[3]+ko+kc);
                bf16x8 c0v = ld16(bL[0]+ko+kc), c1 = ld16(bL[1]+ko+kc), c2 = ld16(bL[2]+ko+kc), c3 = ld16(bL[3]+ko+kc);
                mfma16(acc[0],ah,b0); mfma16(acc[1],ah,b1); mfma16(acc[2],ah,b2); mfma16(acc[3],ah,b3);
                mfma16(acc[0],al,b0); mfma16(acc[1],al,b1); mfma16(acc[2],al,b2); mfma16(acc[3],al,b3);
                mfma16(acc[0],ah,c0v); mfma16(acc[1],ah,c1); mfma16(acc[2],ah,c2); mfma16(acc[3],ah,c3);
            }
        }
        if (!seg) {  // + th_prev @ Whh^T, K=64
            const ush* pah = thHp + b*TDIM + kg*8;
            const ush* pal = thLp + b*TDIM + kg*8;
            #pragma unroll
            for (int kc = 0; kc < 64; kc += 32) {
                bf16x8 ah = ld16(pah + kc);
                bf16x8 al = ld16(pal + kc);
                #pragma unroll
                for (int cf = 0; cf < 4; ++cf) {
                    int j = c0 + cf*16 + l15;
                    bf16x8 bh = ld16(WhhH + j*TDIM + kg*8 + kc);
                    bf16x8 bl = ld16(WhhL + j*TDIM + kg*8 + kc);
                    mfma16(acc[cf], ah, bh);
                    mfma16(acc[cf], al, bh);
                    mfma16(acc[cf], ah, bl);
                }
            }
        }
        float* out = seg ? gbufO : gbufE;
        #pragma unroll
        for (int r = 0; r < 4; ++r) {
            int row = r0 + w*16 + kg*4 + r;
            #pragma unroll
            for (int cf = 0; cf < 4; ++cf) {
                int col = c0 + cf*16 + l15;
                out[row*G4 + col] = acc[cf][r];
            }
        }
    } else {
        const int q = bid - 48;
        const int rt = q / 24, ct = q - rt*24;
        const int s0 = rt*64, c0 = ct*64;
        const int* pp = perm + p*448;
        if (pp[s0] < 0) return;
        const int RB = rbarr[p];
        const bool left = (s0 < RB);
        int ar = pp[s0 + w*16 + l15]; if (ar < 0) ar = 0;
        const ush* pah = (left ? tokH + (ar*64 + p)*KP : accHp + ar*KP) + kg*8;
        const ush* pal = (left ? tokL + (ar*64 + p)*KP : accLp + ar*KP) + kg*8;
        const ush* WBh = left ? ULh : URh;
        const ush* WBl = left ? ULl : URl;
        const ush* bH[4]; const ush* bL[4];
        #pragma unroll
        for (int cf = 0; cf < 4; ++cf) {
            int j = c0 + cf*16 + l15; if (j > G5-1) j = G5-1;
            bH[cf] = WBh + j*KP + kg*8;
            bL[cf] = WBl + j*KP + kg*8;
        }
        #pragma unroll
        for (int kc = 0; kc < KP; kc += 32) {
            bf16x8 ah = ld16(pah + kc);
            bf16x8 al = ld16(pal + kc);
            bf16x8 b0 = ld16(bH[0]+kc), b1 = ld16(bH[1]+kc), b2 = ld16(bH[2]+kc), b3 = ld16(bH[3]+kc);
            bf16x8 c0v = ld16(bL[0]+kc), c1 = ld16(bL[1]+kc), c2 = ld16(bL[2]+kc), c3 = ld16(bL[3]+kc);
            mfma16(acc[0],ah,b0); mfma16(acc[1],ah,b1); mfma16(acc[2],ah,b2); mfma16(acc[3],ah,b3);
            mfma16(acc[0],al,b0); mfma16(acc[1],al,b1); mfma16(acc[2],al,b2); mfma16(acc[3],al,b3);
            mfma16(acc[0],ah,c0v); mfma16(acc[1],ah,c1); mfma16(acc[2],ah,c2); mfma16(acc[3],ah,c3);
        }
        #pragma unroll
        for (int r = 0; r < 4; ++r) {
            int pr = pp[s0 + w*16 + kg*4 + r];
            if (pr < 0) continue;
            #pragma unroll
            for (int cf = 0; cf < 4; ++cf) {
                int col = c0 + cf*16 + l15;
                if (col < G5) Pbuf[pr*G5 + col] = acc[cf][r];
            }
        }
    }
}

// ---------------- kernel B: sequential core (tracking LSTMs, Wc matvec, tree update) ----------------
__global__ __launch_bounds__(256) void k_pairB(int p,
    const float* __restrict__ seq, const int* __restrict__ trans,
    const float* __restrict__ Whh, const float* __restrict__ Wc,
    const float* __restrict__ Uhb, const float* __restrict__ bsum,
    const float* __restrict__ gbufE, const float* __restrict__ gbufO,
    const float* __restrict__ Pbuf,
    ush* __restrict__ thH, ush* __restrict__ thL, float* __restrict__ tc_buf,
    float* __restrict__ acc_c, float* __restrict__ acc_h,
    ush* __restrict__ accHp, ush* __restrict__ accLp)
{
    __shared__ __align__(16) float thl[4][64], tcl[4][64], gel[4][256];
    __shared__ __align__(16) float g5l[4][G5];
    const int tid = threadIdx.x;
    const int r0 = blockIdx.x*4;
    const int row = tid >> 6, d = tid & 63;
    const int b = r0 + row;

    // tracking LSTM even (matvec already folded into gbufE via MFMA)
    {
        float gi = gbufE[b*G4 + d]        + bsum[d];
        float gf = gbufE[b*G4 + 64 + d]   + bsum[64 + d];
        float gg = gbufE[b*G4 + 128 + d]  + bsum[128 + d];
        float go = gbufE[b*G4 + 192 + d]  + bsum[192 + d];
        float tcp = tc_buf[b*TDIM + d];
        float tce = sigm(gf)*tcp + sigm(gi)*tanhf(gg);
        float the = sigm(go)*tanhf(tce);
        thl[row][d] = the; tcl[row][d] = tce;
    }
    __syncthreads();
    // odd matvec: th_even @ Whh^T (each thread: one j, 4 rows)
    {
        int j = tid;
        float s[4] = {0.f,0.f,0.f,0.f};
        #pragma unroll
        for (int k = 0; k < 64; k += 4) {
            float4 wv = *(const float4*)&Whh[j*TDIM + k];
            #pragma unroll
            for (int rr = 0; rr < 4; ++rr) {
                float4 t4 = *(const float4*)&thl[rr][k];
                s[rr] += t4.x*wv.x + t4.y*wv.y + t4.z*wv.z + t4.w*wv.w;
            }
        }
        float bs = bsum[j];
        #pragma unroll
        for (int rr = 0; rr < 4; ++rr)
            gel[rr][j] = gbufO[(r0+rr)*G4 + j] + bs + s[rr];
    }
    __syncthreads();
    // tracking LSTM odd
    {
        float gi = gel[row][d], gf = gel[row][64+d], gg = gel[row][128+d], go = gel[row][192+d];
        float tco = sigm(gf)*tcl[row][d] + sigm(gi)*tanhf(gg);
        float tho = sigm(go)*tanhf(tco);
        tc_buf[b*TDIM + d] = tco;
        ush h = f2bf(tho);
        thH[b*TDIM + d] = h; thL[b*TDIM + d] = f2bf(tho - bf2f(h));
        __syncthreads();
        thl[row][d] = tho;
    }
    __syncthreads();
    // tree gates: g5 = P + Uhb + th_odd @ Wc^T  (each thread: one col, 4 rows)
    for (int c = tid; c < G5; c += 256) {
        float s[4] = {0.f,0.f,0.f,0.f};
        #pragma unroll
        for (int k = 0; k < 64; k += 4) {
            float4 wv = *(const float4*)&Wc[c*TDIM + k];
            #pragma unroll
            for (int rr = 0; rr < 4; ++rr) {
                float4 t4 = *(const float4*)&thl[rr][k];
                s[rr] += t4.x*wv.x + t4.y*wv.y + t4.z*wv.z + t4.w*wv.w;
            }
        }
        float ub = Uhb[c];
        #pragma unroll
        for (int rr = 0; rr < 4; ++rr)
            g5l[rr][c] = Pbuf[(r0+rr)*G5 + c] + ub + s[rr];
    }
    __syncthreads();
    // tree-LSTM elementwise + acc update
    for (int idx = tid; idx < 4*HH; idx += 256) {
        int rr = idx / HH, c = idx - rr*HH;
        int bb = r0 + rr;
        bool left = (trans[bb*TT + 2*p + 1] == 2);
        float ch = left ? seq[bb*SEQB + p*600 + HH + c] : acc_c[bb*HH + c];
        float gi = g5l[rr][c], go = g5l[rr][HH+c], gfh = g5l[rr][2*HH+c], gfc = g5l[rr][3*HH+c], gu = g5l[rr][4*HH+c];
        float cj = sigm(gi)*tanhf(gu) + (sigm(gfh) + sigm(gfc))*ch;
        float hj = sigm(go)*tanhf(cj);
        acc_c[bb*HH + c] = cj;
        acc_h[bb*HH + c] = hj;
        ush h = f2bf(hj);
        accHp[bb*KP + c] = h; accLp[bb*KP + c] = f2bf(hj - bf2f(h));
    }
}

// ---------------- output ----------------
__global__ void k_out(const float* __restrict__ acc_h, float* __restrict__ out)
{
    int i = blockIdx.x*blockDim.x + threadIdx.x;
    if (i < BB*HH) out[i] = acc_h[i];
}

extern "C" void kernel_launch(void* const* d_in, const int* in_sizes, int n_in,
                              void* d_out, int out_size, void* d_ws, size_t ws_size,
                              hipStream_t stream)
{
    const float* seq  = (const float*)d_in[0];
    const int*   trans= (const int*)d_in[1];
    const float* Wc   = (const float*)d_in[2];
    const float* Uhw  = (const float*)d_in[3];
    const float* Uhb  = (const float*)d_in[4];
    const float* Ulw  = (const float*)d_in[5];
    const float* Urw  = (const float*)d_in[6];
    const float* Wih  = (const float*)d_in[7];
    const float* Whh  = (const float*)d_in[8];
    const float* bih  = (const float*)d_in[9];
    const float* bhh  = (const float*)d_in[10];
    const float* th0  = (const float*)d_in[11];
    const float* tc0  = (const float*)d_in[12];
    float* out = (float*)d_out;

    char* w = (char*)d_ws;
    size_t off = 0;
    auto alloc = [&](size_t nbytes) {
        void* ptr = w + off;
        off = (off + nbytes + 255) & ~(size_t)255;
        return ptr;
    };
    ush* tokH = (ush*)alloc((size_t)BB*LSEQ*KP*2);
    ush* tokL = (ush*)alloc((size_t)BB*LSEQ*KP*2);
    ush* accH = (ush*)alloc((size_t)BB*KP*2);
    ush* accL = (ush*)alloc((size_t)BB*KP*2);
    ush* ULh  = (ush*)alloc((size_t)G5*KP*2);
    ush* ULl  = (ush*)alloc((size_t)G5*KP*2);
    ush* URh  = (ush*)alloc((size_t)G5*KP*2);
    ush* URl  = (ush*)alloc((size_t)G5*KP*2);
    ush* WihH = (ush*)alloc((size_t)G4*3*KP*2);
    ush* WihL = (ush*)alloc((size_t)G4*3*KP*2);
    ush* WhhH = (ush*)alloc((size_t)G4*TDIM*2);
    ush* WhhL = (ush*)alloc((size_t)G4*TDIM*2);
    ush* thH  = (ush*)alloc((size_t)BB*TDIM*2);
    ush* thL  = (ush*)alloc((size_t)BB*TDIM*2);
    float* bsum  = (float*)alloc((size_t)G4*4);
    float* gbufE = (float*)alloc((size_t)BB*G4*4);
    float* gbufO = (float*)alloc((size_t)BB*G4*4);
    float* Pbuf  = (float*)alloc((size_t)BB*G5*4);
    float* tcb   = (float*)alloc((size_t)BB*TDIM*4);
    float* acc_c = (float*)alloc((size_t)BB*HH*4);
    float* acc_h = (float*)alloc((size_t)BB*HH*4);
    int* perm  = (int*)alloc((size_t)NP*448*4);
    int* rbarr = (int*)alloc((size_t)NP*4);

    k_wprep<<<960, 256, 0, stream>>>(Uhw, Ulw, Urw, Wih, Whh, bih, bhh,
                                     ULh, ULl, URh, URl, WihH, WihL, WhhH, WhhL, bsum);
    k_cvt<<<2048, 256, 0, stream>>>(seq, tokH, tokL);
    k_init<<<512, 256, 0, stream>>>(seq, th0, tc0, tokH, tokL,
                                    accH, accL, acc_c, acc_h, thH, thL, tcb);
    k_prep2<<<NP, 448, 0, stream>>>(trans, perm, rbarr);

    for (int p = 0; p < NP; ++p) {
        k_pairA<<<216, 256, 0, stream>>>(p, tokH, tokL, accH, accL, thH, thL,
                                         ULh, ULl, URh, URl, WihH, WihL, WhhH, WhhL,
                                         perm, rbarr, gbufE, gbufO, Pbuf);
        k_pairB<<<96, 256, 0, stream>>>(p, seq, trans, Whh, Wc, Uhb, bsum,
                                        gbufE, gbufO, Pbuf,
                                        thH, thL, tcb, acc_c, acc_h, accH, accL);
    }
    k_out<<<(BB*HH + 255)/256, 256, 0, stream>>>(acc_h, out);
}